// Round 9
// baseline (305.660 us; speedup 1.0000x reference)
//
#include <hip/hip_runtime.h>

#define EPS 1e-5f

typedef __bf16 bf16x8 __attribute__((ext_vector_type(8)));
typedef __bf16 bf16x4 __attribute__((ext_vector_type(4)));
typedef unsigned short ushort8 __attribute__((ext_vector_type(8)));
typedef float f32x4 __attribute__((ext_vector_type(4)));

static __device__ __forceinline__ unsigned short f2bf(float f) {
  unsigned int u = __float_as_uint(f);
  u += 0x7fffu + ((u >> 16) & 1u);
  return (unsigned short)(u >> 16);
}

// ---------------- ws layout (bytes) ----------------
// h2   (bf16, NHWC [128][1024][128])             : 0 .. 33554432
// w1b  (bf16, [128 oc][512 c], bn2-scale folded) : 33554432 .. +131072
// w2b  (bf16, [32 oc][9 tap][128 c])             : 33685504 .. +73728
// bias2(f32 [128])                               : 33759232 .. +512
// psum (f32 [512][8])                            : 33763840 .. +16384
// psq  (f32 [512][8])                            : 33780224 .. +16384

// ---- kernel 1: bn1 partial stats, PURE READ (+ weight prep tail blocks) ----
__global__ void __launch_bounds__(256) stats_kernel(
    const float* __restrict__ x,
    float* __restrict__ psum, float* __restrict__ psq,
    const float* __restrict__ w1, const float* __restrict__ gamma2,
    const float* __restrict__ beta2, const float* __restrict__ mean2,
    const float* __restrict__ var2, const float* __restrict__ w2,
    unsigned short* __restrict__ w1b, unsigned short* __restrict__ w2b,
    float* __restrict__ bias2) {
  const int t = threadIdx.x;
  if (blockIdx.x >= 4096) {
    int idx = (blockIdx.x - 4096) * 256 + t;
    if (idx < 128 * 512) {
      int oc = idx >> 9;
      float s2 = gamma2[oc] * rsqrtf(var2[oc] + EPS);
      w1b[idx] = f2bf(w1[idx] * s2);
    } else if (idx < 128 * 512 + 32 * 1152) {
      int i2 = idx - 128 * 512;
      int oc = i2 / 1152;
      int rem = i2 - oc * 1152;
      int tap = rem >> 7;
      int c = rem & 127;
      w2b[i2] = f2bf(w2[(oc * 128 + c) * 9 + tap]);
    } else if (idx < 128 * 512 + 32 * 1152 + 128) {
      int oc = idx - (128 * 512 + 32 * 1152);
      float s2 = gamma2[oc] * rsqrtf(var2[oc] + EPS);
      bias2[oc] = beta2[oc] - mean2[oc] * s2;
    }
    return;
  }
  const int c = blockIdx.x & 511;
  const int nq = blockIdx.x >> 9;
  float sum = 0.f, sq = 0.f;
  const f32x4* __restrict__ x4 = (const f32x4*)x;
#pragma unroll 8
  for (int i = 0; i < 16; ++i) {
    const int n = nq * 16 + i;
    f32x4 v = x4[(((size_t)n * 512 + c) << 8) + t];
    sum += v[0] + v[1] + v[2] + v[3];
    sq += v[0] * v[0] + v[1] * v[1] + v[2] * v[2] + v[3] * v[3];
  }
  __shared__ float ls[2][4];
  for (int off = 32; off > 0; off >>= 1) {
    sum += __shfl_down(sum, off);
    sq += __shfl_down(sq, off);
  }
  const int w = t >> 6;
  if ((t & 63) == 0) { ls[0][w] = sum; ls[1][w] = sq; }
  __syncthreads();
  if (t == 0) {
    psum[c * 8 + nq] = ls[0][0] + ls[0][1] + ls[0][2] + ls[0][3];
    psq[c * 8 + nq] = ls[1][0] + ls[1][1] + ls[1][2] + ls[1][3];
  }
}

// ---- kernel 2: concat-copy of x + bn1+relu -> 1x1 conv -> bn2+relu -> h2 ----
// 512 blocks (128 n x 4 quarters), 4 waves, wave = 128 oc x 64 px.
// LDS-FREE: B-fragments gathered directly from x (coalesced dwords),
// x values nt-stored to out (the dense-concat copy) on the way through.
// No barriers in the K-loop; k+1 prefetched into registers.
__global__ void __launch_bounds__(256, 2) conv1_kernel(
    const float* __restrict__ x, float* __restrict__ out,
    const unsigned short* __restrict__ w1b,
    const float* __restrict__ psum, const float* __restrict__ psq,
    const float* __restrict__ g1, const float* __restrict__ be1,
    const float* __restrict__ bias2, unsigned short* __restrict__ h2) {
  const int t = threadIdx.x;
  __shared__ float s1s[512], b1s[512];
  for (int cc = t; cc < 512; cc += 256) {
    float S = 0.f, Q = 0.f;
#pragma unroll
    for (int qq = 0; qq < 8; ++qq) { S += psum[cc * 8 + qq]; Q += psq[cc * 8 + qq]; }
    float mean = S * (1.0f / 131072.0f);
    float var = Q * (1.0f / 131072.0f) - mean * mean;
    float s = g1[cc] * rsqrtf(var + EPS);
    s1s[cc] = s;
    b1s[cc] = be1[cc] - mean * s;
  }
  __syncthreads();

  const int lane = t & 63;
  const int wv = t >> 6;
  const int n = 127 - (blockIdx.x >> 2);
  const int q = blockIdx.x & 3;
  const int l15 = lane & 15;
  const int kb = lane >> 4;
  const int p = q * 256 + wv * 64 + l15;  // px for g=0; +16 per g

  f32x4 acc[8][4];
#pragma unroll
  for (int m = 0; m < 8; ++m)
#pragma unroll
    for (int g = 0; g < 4; ++g) acc[m][g] = (f32x4){0.f, 0.f, 0.f, 0.f};

  const float* __restrict__ xn = x + (size_t)n * 524288;
  float* __restrict__ outn = out + (size_t)n * 544 * 1024;

  float cur[4][8], nxt[4][8];
#pragma unroll
  for (int g = 0; g < 4; ++g)
#pragma unroll
    for (int j = 0; j < 8; ++j)
      cur[g][j] = xn[(size_t)(kb * 8 + j) * 1024 + p + g * 16];

  for (int k = 0; k < 16; ++k) {
    const int cb = k * 32 + kb * 8;
    // issue next K-slice loads first (full MFMA phase to land)
    if (k < 15) {
#pragma unroll
      for (int g = 0; g < 4; ++g)
#pragma unroll
        for (int j = 0; j < 8; ++j)
          nxt[g][j] = xn[(size_t)(cb + 32 + j) * 1024 + p + g * 16];
    }
    // dense-concat copy: stream cur out (fire-and-forget nt stores)
#pragma unroll
    for (int g = 0; g < 4; ++g)
#pragma unroll
      for (int j = 0; j < 8; ++j)
        __builtin_nontemporal_store(cur[g][j],
                                    &outn[(size_t)(cb + j) * 1024 + p + g * 16]);
    // bn1 + relu + cvt -> B fragments
    float sv[8], bv[8];
#pragma unroll
    for (int j = 0; j < 8; ++j) { sv[j] = s1s[cb + j]; bv[j] = b1s[cb + j]; }
    bf16x8 bf[4];
#pragma unroll
    for (int g = 0; g < 4; ++g) {
      bf16x8 tmp;
#pragma unroll
      for (int j = 0; j < 8; ++j)
        tmp[j] = (__bf16)fmaxf(fmaf(cur[g][j], sv[j], bv[j]), 0.f);
      bf[g] = tmp;
    }
    // MFMA
#pragma unroll
    for (int m = 0; m < 8; ++m) {
      bf16x8 af = *(const bf16x8*)(w1b + (size_t)(m * 16 + l15) * 512 + cb);
#pragma unroll
      for (int g = 0; g < 4; ++g)
        acc[m][g] = __builtin_amdgcn_mfma_f32_16x16x32_bf16(af, bf[g], acc[m][g], 0, 0, 0);
    }
#pragma unroll
    for (int g = 0; g < 4; ++g)
#pragma unroll
      for (int j = 0; j < 8; ++j) cur[g][j] = nxt[g][j];
  }

  // epilogue: h2[n][p][oc] = relu(acc + bias2) (plain stores -> L3 for conv2)
#pragma unroll
  for (int m = 0; m < 8; ++m) {
    const int ocb = m * 16 + kb * 4;
    float bz0 = bias2[ocb + 0], bz1 = bias2[ocb + 1];
    float bz2 = bias2[ocb + 2], bz3 = bias2[ocb + 3];
#pragma unroll
    for (int g = 0; g < 4; ++g) {
      const int pp = q * 256 + wv * 64 + g * 16 + l15;
      bf16x4 hv;
      hv[0] = (__bf16)fmaxf(acc[m][g][0] + bz0, 0.f);
      hv[1] = (__bf16)fmaxf(acc[m][g][1] + bz1, 0.f);
      hv[2] = (__bf16)fmaxf(acc[m][g][2] + bz2, 0.f);
      hv[3] = (__bf16)fmaxf(acc[m][g][3] + bz3, 0.f);
      *(bf16x4*)(h2 + ((size_t)n * 1024 + pp) * 128 + ocb) = hv;
    }
  }
}

// ---- kernel 3: 3x3 conv (pad 1) h2 -> out[:, 512:544] ----
// 1024 blocks (128 n x 8 slabs), 4 waves, wave = 32 oc x 32 px.
__global__ void __launch_bounds__(256) conv2_kernel(
    const unsigned short* __restrict__ h2, const unsigned short* __restrict__ w2b,
    float* __restrict__ out) {
  const int t = threadIdx.x;
  const int lane = t & 63;
  const int wv = t >> 6;
  const int n = blockIdx.x >> 3;
  const int pbase = (blockIdx.x & 7) * 128 + wv * 32;
  const int l15 = lane & 15;
  const int kb = lane >> 4;

  f32x4 acc[2][2];
#pragma unroll
  for (int m = 0; m < 2; ++m)
#pragma unroll
    for (int g = 0; g < 2; ++g) acc[m][g] = (f32x4){0.f, 0.f, 0.f, 0.f};

  const unsigned short* __restrict__ h2n = h2 + (size_t)n * 1024 * 128;

#pragma unroll
  for (int tap = 0; tap < 9; ++tap) {
    const int dy = tap / 3 - 1;
    const int dx = tap % 3 - 1;
#pragma unroll
    for (int c0 = 0; c0 < 128; c0 += 32) {
      const int cb = c0 + kb * 8;
      bf16x8 af[2];
#pragma unroll
      for (int m = 0; m < 2; ++m)
        af[m] = *(const bf16x8*)(w2b + (size_t)(m * 16 + l15) * 1152 + tap * 128 + cb);
#pragma unroll
      for (int g = 0; g < 2; ++g) {
        const int p = pbase + g * 16 + l15;
        const int y = (p >> 5) & 31;
        const int xx = p & 31;
        const int y2 = y + dy;
        const int x2 = xx + dx;
        bf16x8 bv = __builtin_bit_cast(bf16x8, (ushort8){0, 0, 0, 0, 0, 0, 0, 0});
        if (y2 >= 0 && y2 < 32 && x2 >= 0 && x2 < 32)
          bv = *(const bf16x8*)(h2n + ((size_t)(y2 * 32 + x2)) * 128 + cb);
#pragma unroll
        for (int m = 0; m < 2; ++m)
          acc[m][g] = __builtin_amdgcn_mfma_f32_16x16x32_bf16(af[m], bv, acc[m][g], 0, 0, 0);
      }
    }
  }

#pragma unroll
  for (int m = 0; m < 2; ++m) {
    const int oc = m * 16 + kb * 4;
#pragma unroll
    for (int g = 0; g < 2; ++g) {
      const int p = pbase + g * 16 + l15;
#pragma unroll
      for (int r = 0; r < 4; ++r)
        __builtin_nontemporal_store(
            acc[m][g][r], &out[((size_t)n * 544 + 512 + oc + r) * 1024 + p]);
    }
  }
}

extern "C" void kernel_launch(void* const* d_in, const int* in_sizes, int n_in,
                              void* d_out, int out_size, void* d_ws, size_t ws_size,
                              hipStream_t stream) {
  const float* x = (const float*)d_in[0];
  const float* gamma1 = (const float*)d_in[1];
  const float* beta1 = (const float*)d_in[2];
  const float* w1 = (const float*)d_in[3];
  const float* gamma2 = (const float*)d_in[4];
  const float* beta2 = (const float*)d_in[5];
  const float* mean2 = (const float*)d_in[6];
  const float* var2 = (const float*)d_in[7];
  const float* w2 = (const float*)d_in[8];
  float* out = (float*)d_out;

  char* ws = (char*)d_ws;
  unsigned short* h2 = (unsigned short*)ws;
  unsigned short* w1b = (unsigned short*)(ws + 33554432);
  unsigned short* w2b = (unsigned short*)(ws + 33685504);
  float* bias2 = (float*)(ws + 33759232);
  float* psum = (float*)(ws + 33763840);
  float* psq = (float*)(ws + 33780224);

  stats_kernel<<<4497, 256, 0, stream>>>(x, psum, psq,
                                         w1, gamma2, beta2, mean2, var2, w2,
                                         w1b, w2b, bias2);
  conv1_kernel<<<512, 256, 0, stream>>>(x, out, w1b, psum, psq,
                                        gamma1, beta1, bias2, h2);
  conv2_kernel<<<1024, 256, 0, stream>>>(h2, w2b, out);
}

// Round 10
// 247.394 us; speedup vs baseline: 1.2355x; 1.2355x over previous
//
#include <hip/hip_runtime.h>

#define EPS 1e-5f

typedef __bf16 bf16x8 __attribute__((ext_vector_type(8)));
typedef __bf16 bf16x4 __attribute__((ext_vector_type(4)));
typedef unsigned short ushort8 __attribute__((ext_vector_type(8)));
typedef float f32x4 __attribute__((ext_vector_type(4)));

static __device__ __forceinline__ unsigned short f2bf(float f) {
  unsigned int u = __float_as_uint(f);
  u += 0x7fffu + ((u >> 16) & 1u);
  return (unsigned short)(u >> 16);
}

// ---------------- ws layout (bytes) ----------------
// h2   (bf16, NHWC [128][1024][128])             : 0 .. 33554432
// w1b  (bf16, [128 oc][512 c], bn2-scale folded) : 33554432 .. +131072
// w2b  (bf16, [32 oc][9 tap][128 c])             : 33685504 .. +73728
// bias2(f32 [128])                               : 33759232 .. +512
// psum (f32 [512][8])                            : 33763840 .. +16384
// psq  (f32 [512][8])                            : 33780224 .. +16384

// ---- kernel 1: bn1 partial stats + concat-copy of x (+ weight prep blocks) ----
// blocks 0..4095: (nq,c), nq-major so n=112..127 x-lines are freshest in L3.
// x loads PLAIN (allocate L3 for conv1 reuse); out stores nontemporal.
__global__ void __launch_bounds__(256) k1_kernel(
    const float* __restrict__ x, float* __restrict__ out,
    float* __restrict__ psum, float* __restrict__ psq,
    const float* __restrict__ w1, const float* __restrict__ gamma2,
    const float* __restrict__ beta2, const float* __restrict__ mean2,
    const float* __restrict__ var2, const float* __restrict__ w2,
    unsigned short* __restrict__ w1b, unsigned short* __restrict__ w2b,
    float* __restrict__ bias2) {
  const int t = threadIdx.x;
  if (blockIdx.x >= 4096) {
    int idx = (blockIdx.x - 4096) * 256 + t;
    if (idx < 128 * 512) {
      int oc = idx >> 9;
      float s2 = gamma2[oc] * rsqrtf(var2[oc] + EPS);
      w1b[idx] = f2bf(w1[idx] * s2);
    } else if (idx < 128 * 512 + 32 * 1152) {
      int i2 = idx - 128 * 512;
      int oc = i2 / 1152;
      int rem = i2 - oc * 1152;
      int tap = rem >> 7;
      int c = rem & 127;
      w2b[i2] = f2bf(w2[(oc * 128 + c) * 9 + tap]);
    } else if (idx < 128 * 512 + 32 * 1152 + 128) {
      int oc = idx - (128 * 512 + 32 * 1152);
      float s2 = gamma2[oc] * rsqrtf(var2[oc] + EPS);
      bias2[oc] = beta2[oc] - mean2[oc] * s2;
    }
    return;
  }
  const int c = blockIdx.x & 511;
  const int nq = blockIdx.x >> 9;
  float sum = 0.f, sq = 0.f;
  const f32x4* __restrict__ x4 = (const f32x4*)x;
  f32x4* out4 = (f32x4*)out;
#pragma unroll 8
  for (int i = 0; i < 16; ++i) {
    const int n = nq * 16 + i;
    f32x4 v = x4[(((size_t)n * 512 + c) << 8) + t];
    __builtin_nontemporal_store(v, &out4[(((size_t)n * 544 + c) << 8) + t]);
    sum += v[0] + v[1] + v[2] + v[3];
    sq += v[0] * v[0] + v[1] * v[1] + v[2] * v[2] + v[3] * v[3];
  }
  __shared__ float ls[2][4];
  for (int off = 32; off > 0; off >>= 1) {
    sum += __shfl_down(sum, off);
    sq += __shfl_down(sq, off);
  }
  const int w = t >> 6;
  if ((t & 63) == 0) { ls[0][w] = sum; ls[1][w] = sq; }
  __syncthreads();
  if (t == 0) {
    psum[c * 8 + nq] = ls[0][0] + ls[0][1] + ls[0][2] + ls[0][3];
    psq[c * 8 + nq] = ls[1][0] + ls[1][1] + ls[1][2] + ls[1][3];
  }
}

// ---- kernel 2: bn1+relu -> 1x1 conv -> bn2+relu -> h2 (bf16 NHWC), from x ----
// 512 blocks (128 n x 4 quarters), 4 waves, wave = 128 oc x 64 px.
// Double-buffered LDS tile [32 ch][260 px] (R7 layout), ONE barrier per K-step.
// n DESCENDING (L3 tail reuse). bn1 scale/shift from psum/psq in prologue.
__global__ void __launch_bounds__(256, 2) conv1_kernel(
    const float* __restrict__ x, const unsigned short* __restrict__ w1b,
    const float* __restrict__ psum, const float* __restrict__ psq,
    const float* __restrict__ g1, const float* __restrict__ be1,
    const float* __restrict__ bias2, unsigned short* __restrict__ h2) {
  const int t = threadIdx.x;
  __shared__ float s1s[512], b1s[512];
  __shared__ __align__(16) unsigned short tile0[32 * 260];
  __shared__ __align__(16) unsigned short tile1[32 * 260];

  for (int cc = t; cc < 512; cc += 256) {
    float S = 0.f, Q = 0.f;
#pragma unroll
    for (int qq = 0; qq < 8; ++qq) { S += psum[cc * 8 + qq]; Q += psq[cc * 8 + qq]; }
    float mean = S * (1.0f / 131072.0f);
    float var = Q * (1.0f / 131072.0f) - mean * mean;
    float s = g1[cc] * rsqrtf(var + EPS);
    s1s[cc] = s;
    b1s[cc] = be1[cc] - mean * s;
  }
  __syncthreads();

  const int lane = t & 63;
  const int wv = t >> 6;
  const int n = 127 - (blockIdx.x >> 2);
  const int q = blockIdx.x & 3;
  const int l15 = lane & 15;
  const int kb = lane >> 4;

  f32x4 acc[8][4];
#pragma unroll
  for (int m = 0; m < 8; ++m)
#pragma unroll
    for (int g = 0; g < 4; ++g) acc[m][g] = (f32x4){0.f, 0.f, 0.f, 0.f};

  const f32x4* __restrict__ xq = (const f32x4*)(x + (size_t)n * 524288 + q * 256);

  f32x4 va[8], vb[8];

#define LOADV(vv, kk)                                               \
  {                                                                 \
    _Pragma("unroll") for (int i = 0; i < 8; ++i)                   \
        vv[i] = xq[(size_t)((kk) * 32 + wv * 8 + i) * 256 + lane];  \
  }
#define STAGE(tl, kk, vv)                                              \
  {                                                                    \
    _Pragma("unroll") for (int i = 0; i < 8; ++i) {                    \
      const int c = (kk) * 32 + wv * 8 + i;                            \
      const float s = s1s[c], b = b1s[c];                              \
      bf16x4 bv;                                                       \
      bv[0] = (__bf16)fmaxf(fmaf(vv[i][0], s, b), 0.f);                \
      bv[1] = (__bf16)fmaxf(fmaf(vv[i][1], s, b), 0.f);                \
      bv[2] = (__bf16)fmaxf(fmaf(vv[i][2], s, b), 0.f);                \
      bv[3] = (__bf16)fmaxf(fmaf(vv[i][3], s, b), 0.f);                \
      *(bf16x4*)&tl[(size_t)(wv * 8 + i) * 260 + 4 * lane] = bv;       \
    }                                                                  \
  }
#define FRAGMFMA(tl, kk)                                                    \
  {                                                                         \
    bf16x8 bf[4];                                                           \
    _Pragma("unroll") for (int g = 0; g < 4; ++g) {                         \
      const int pl = wv * 64 + g * 16 + l15;                                \
      bf16x8 tmp;                                                           \
      _Pragma("unroll") for (int j = 0; j < 8; ++j)                         \
          tmp[j] = __builtin_bit_cast(__bf16, tl[(kb * 8 + j) * 260 + pl]); \
      bf[g] = tmp;                                                          \
    }                                                                       \
    _Pragma("unroll") for (int m = 0; m < 8; ++m) {                         \
      bf16x8 af =                                                           \
          *(const bf16x8*)(w1b + (size_t)(m * 16 + l15) * 512 + (kk) * 32 + \
                           kb * 8);                                         \
      _Pragma("unroll") for (int g = 0; g < 4; ++g) acc[m][g] =             \
          __builtin_amdgcn_mfma_f32_16x16x32_bf16(af, bf[g], acc[m][g], 0,  \
                                                  0, 0);                    \
    }                                                                       \
  }

  LOADV(va, 0);
  STAGE(tile0, 0, va);
  LOADV(va, 1);
  __syncthreads();

  for (int k2 = 0; k2 < 8; ++k2) {
    const int ke = 2 * k2, ko = 2 * k2 + 1;
    // even step: read tile0, stage ke+1 -> tile1
    STAGE(tile1, ke + 1, va);
    if (ke + 2 < 16) LOADV(vb, ke + 2);
    FRAGMFMA(tile0, ke);
    __syncthreads();
    // odd step: read tile1, stage ko+1 -> tile0
    if (ko + 1 < 16) {
      STAGE(tile0, ko + 1, vb);
      LOADV(va, ko + 2);
    }
    FRAGMFMA(tile1, ko);
    __syncthreads();
  }
#undef LOADV
#undef STAGE
#undef FRAGMFMA

  // epilogue: h2[n][p][oc] = relu(acc + bias2)  (plain stores -> cache for conv2)
#pragma unroll
  for (int m = 0; m < 8; ++m) {
    const int ocb = m * 16 + kb * 4;
    float bz0 = bias2[ocb + 0], bz1 = bias2[ocb + 1];
    float bz2 = bias2[ocb + 2], bz3 = bias2[ocb + 3];
#pragma unroll
    for (int g = 0; g < 4; ++g) {
      const int p = q * 256 + wv * 64 + g * 16 + l15;
      bf16x4 hv;
      hv[0] = (__bf16)fmaxf(acc[m][g][0] + bz0, 0.f);
      hv[1] = (__bf16)fmaxf(acc[m][g][1] + bz1, 0.f);
      hv[2] = (__bf16)fmaxf(acc[m][g][2] + bz2, 0.f);
      hv[3] = (__bf16)fmaxf(acc[m][g][3] + bz3, 0.f);
      *(bf16x4*)(h2 + ((size_t)n * 1024 + p) * 128 + ocb) = hv;
    }
  }
}

// ---- kernel 3: 3x3 conv (pad 1) h2 -> out[:, 512:544] ----
// 1024 blocks (128 n x 8 slabs), 4 waves, wave = 32 oc x 32 px.
__global__ void __launch_bounds__(256) conv2_kernel(
    const unsigned short* __restrict__ h2, const unsigned short* __restrict__ w2b,
    float* __restrict__ out) {
  const int t = threadIdx.x;
  const int lane = t & 63;
  const int wv = t >> 6;
  const int n = blockIdx.x >> 3;
  const int pbase = (blockIdx.x & 7) * 128 + wv * 32;
  const int l15 = lane & 15;
  const int kb = lane >> 4;

  f32x4 acc[2][2];
#pragma unroll
  for (int m = 0; m < 2; ++m)
#pragma unroll
    for (int g = 0; g < 2; ++g) acc[m][g] = (f32x4){0.f, 0.f, 0.f, 0.f};

  const unsigned short* __restrict__ h2n = h2 + (size_t)n * 1024 * 128;

#pragma unroll
  for (int tap = 0; tap < 9; ++tap) {
    const int dy = tap / 3 - 1;
    const int dx = tap % 3 - 1;
#pragma unroll
    for (int c0 = 0; c0 < 128; c0 += 32) {
      const int cb = c0 + kb * 8;
      bf16x8 af[2];
#pragma unroll
      for (int m = 0; m < 2; ++m)
        af[m] = *(const bf16x8*)(w2b + (size_t)(m * 16 + l15) * 1152 + tap * 128 + cb);
#pragma unroll
      for (int g = 0; g < 2; ++g) {
        const int p = pbase + g * 16 + l15;
        const int y = (p >> 5) & 31;
        const int xx = p & 31;
        const int y2 = y + dy;
        const int x2 = xx + dx;
        bf16x8 bv = __builtin_bit_cast(bf16x8, (ushort8){0, 0, 0, 0, 0, 0, 0, 0});
        if (y2 >= 0 && y2 < 32 && x2 >= 0 && x2 < 32)
          bv = *(const bf16x8*)(h2n + ((size_t)(y2 * 32 + x2)) * 128 + cb);
#pragma unroll
        for (int m = 0; m < 2; ++m)
          acc[m][g] = __builtin_amdgcn_mfma_f32_16x16x32_bf16(af[m], bv, acc[m][g], 0, 0, 0);
      }
    }
  }

#pragma unroll
  for (int m = 0; m < 2; ++m) {
    const int oc = m * 16 + kb * 4;
#pragma unroll
    for (int g = 0; g < 2; ++g) {
      const int p = pbase + g * 16 + l15;
#pragma unroll
      for (int r = 0; r < 4; ++r)
        __builtin_nontemporal_store(
            acc[m][g][r], &out[((size_t)n * 544 + 512 + oc + r) * 1024 + p]);
    }
  }
}

extern "C" void kernel_launch(void* const* d_in, const int* in_sizes, int n_in,
                              void* d_out, int out_size, void* d_ws, size_t ws_size,
                              hipStream_t stream) {
  const float* x = (const float*)d_in[0];
  const float* gamma1 = (const float*)d_in[1];
  const float* beta1 = (const float*)d_in[2];
  const float* w1 = (const float*)d_in[3];
  const float* gamma2 = (const float*)d_in[4];
  const float* beta2 = (const float*)d_in[5];
  const float* mean2 = (const float*)d_in[6];
  const float* var2 = (const float*)d_in[7];
  const float* w2 = (const float*)d_in[8];
  float* out = (float*)d_out;

  char* ws = (char*)d_ws;
  unsigned short* h2 = (unsigned short*)ws;
  unsigned short* w1b = (unsigned short*)(ws + 33554432);
  unsigned short* w2b = (unsigned short*)(ws + 33685504);
  float* bias2 = (float*)(ws + 33759232);
  float* psum = (float*)(ws + 33763840);
  float* psq = (float*)(ws + 33780224);

  k1_kernel<<<4497, 256, 0, stream>>>(x, out, psum, psq,
                                      w1, gamma2, beta2, mean2, var2, w2,
                                      w1b, w2b, bias2);
  conv1_kernel<<<512, 256, 0, stream>>>(x, w1b, psum, psq, gamma1, beta1,
                                        bias2, h2);
  conv2_kernel<<<1024, 256, 0, stream>>>(h2, w2b, out);
}

// Round 11
// 236.001 us; speedup vs baseline: 1.2952x; 1.0483x over previous
//
#include <hip/hip_runtime.h>

#define EPS 1e-5f

typedef __bf16 bf16x8 __attribute__((ext_vector_type(8)));
typedef __bf16 bf16x4 __attribute__((ext_vector_type(4)));
typedef unsigned short ushort8 __attribute__((ext_vector_type(8)));
typedef float f32x4 __attribute__((ext_vector_type(4)));

static __device__ __forceinline__ unsigned short f2bf(float f) {
  unsigned int u = __float_as_uint(f);
  u += 0x7fffu + ((u >> 16) & 1u);
  return (unsigned short)(u >> 16);
}

// ---------------- ws layout (bytes) ----------------
// h2   (bf16, NHWC [128][1024][128])             : 0 .. 33554432
// w1b  (bf16, [128 oc][512 c], bn2-scale folded) : 33554432 .. +131072
// w2b  (bf16, [32 oc][9 tap][128 c])             : 33685504 .. +73728
// bias2(f32 [128])                               : 33759232 .. +512
// psum (f32 [512][8])                            : 33763840 .. +16384
// psq  (f32 [512][8])                            : 33780224 .. +16384

// ---- kernel 1: bn1 partial stats + concat-copy of x (+ weight prep blocks) ----
__global__ void __launch_bounds__(256) k1_kernel(
    const float* __restrict__ x, float* __restrict__ out,
    float* __restrict__ psum, float* __restrict__ psq,
    const float* __restrict__ w1, const float* __restrict__ gamma2,
    const float* __restrict__ beta2, const float* __restrict__ mean2,
    const float* __restrict__ var2, const float* __restrict__ w2,
    unsigned short* __restrict__ w1b, unsigned short* __restrict__ w2b,
    float* __restrict__ bias2) {
  const int t = threadIdx.x;
  if (blockIdx.x >= 4096) {
    int idx = (blockIdx.x - 4096) * 256 + t;
    if (idx < 128 * 512) {
      int oc = idx >> 9;
      float s2 = gamma2[oc] * rsqrtf(var2[oc] + EPS);
      w1b[idx] = f2bf(w1[idx] * s2);
    } else if (idx < 128 * 512 + 32 * 1152) {
      int i2 = idx - 128 * 512;
      int oc = i2 / 1152;
      int rem = i2 - oc * 1152;
      int tap = rem >> 7;
      int c = rem & 127;
      w2b[i2] = f2bf(w2[(oc * 128 + c) * 9 + tap]);
    } else if (idx < 128 * 512 + 32 * 1152 + 128) {
      int oc = idx - (128 * 512 + 32 * 1152);
      float s2 = gamma2[oc] * rsqrtf(var2[oc] + EPS);
      bias2[oc] = beta2[oc] - mean2[oc] * s2;
    }
    return;
  }
  const int c = blockIdx.x & 511;
  const int nq = blockIdx.x >> 9;
  float sum = 0.f, sq = 0.f;
  const f32x4* __restrict__ x4 = (const f32x4*)x;
  f32x4* out4 = (f32x4*)out;
#pragma unroll 8
  for (int i = 0; i < 16; ++i) {
    const int n = nq * 16 + i;
    f32x4 v = x4[(((size_t)n * 512 + c) << 8) + t];
    __builtin_nontemporal_store(v, &out4[(((size_t)n * 544 + c) << 8) + t]);
    sum += v[0] + v[1] + v[2] + v[3];
    sq += v[0] * v[0] + v[1] * v[1] + v[2] * v[2] + v[3] * v[3];
  }
  __shared__ float ls[2][4];
  for (int off = 32; off > 0; off >>= 1) {
    sum += __shfl_down(sum, off);
    sq += __shfl_down(sq, off);
  }
  const int w = t >> 6;
  if ((t & 63) == 0) { ls[0][w] = sum; ls[1][w] = sq; }
  __syncthreads();
  if (t == 0) {
    psum[c * 8 + nq] = ls[0][0] + ls[0][1] + ls[0][2] + ls[0][3];
    psq[c * 8 + nq] = ls[1][0] + ls[1][1] + ls[1][2] + ls[1][3];
  }
}

// ---- kernel 2: bn1+relu -> 1x1 conv -> bn2+relu -> h2 (bf16 NHWC), from x ----
// 1024 blocks (128 n x 8 slabs of 128 px), 4 waves, wave = 128 oc x 32 px.
// R7's proven inner structure: single LDS tile [32 ch][132 px], STAGE ->
// sync -> FRAG+MFMA -> sync, 1-deep register prefetch. 3 blocks/CU.
__global__ void __launch_bounds__(256, 3) conv1_kernel(
    const float* __restrict__ x, const unsigned short* __restrict__ w1b,
    const float* __restrict__ psum, const float* __restrict__ psq,
    const float* __restrict__ g1, const float* __restrict__ be1,
    const float* __restrict__ bias2, unsigned short* __restrict__ h2) {
  const int t = threadIdx.x;
  __shared__ float s1s[512], b1s[512];
  __shared__ __align__(16) unsigned short tile[32 * 132];

  for (int cc = t; cc < 512; cc += 256) {
    float S = 0.f, Q = 0.f;
#pragma unroll
    for (int qq = 0; qq < 8; ++qq) { S += psum[cc * 8 + qq]; Q += psq[cc * 8 + qq]; }
    float mean = S * (1.0f / 131072.0f);
    float var = Q * (1.0f / 131072.0f) - mean * mean;
    float s = g1[cc] * rsqrtf(var + EPS);
    s1s[cc] = s;
    b1s[cc] = be1[cc] - mean * s;
  }
  __syncthreads();

  const int lane = t & 63;
  const int wv = t >> 6;
  const int n = 127 - (blockIdx.x >> 3);
  const int slab = blockIdx.x & 7;
  const int l15 = lane & 15;
  const int kb = lane >> 4;
  const int tg = t >> 5;    // 0..7: channel quad owner
  const int l31 = t & 31;   // px chunk (4 px)

  f32x4 acc[8][2];
#pragma unroll
  for (int m = 0; m < 8; ++m)
#pragma unroll
    for (int g = 0; g < 2; ++g) acc[m][g] = (f32x4){0.f, 0.f, 0.f, 0.f};

  // f32x4 view of x[n]; element index = ch*256 + slab*32 + l31
  const f32x4* __restrict__ x4n = (const f32x4*)(x + (size_t)n * 524288);
  const int pxoff = slab * 32 + l31;

  f32x4 v[4];

#define LOADV(kk)                                                        \
  {                                                                      \
    _Pragma("unroll") for (int i = 0; i < 4; ++i)                        \
        v[i] = x4n[(size_t)((kk) * 32 + tg * 4 + i) * 256 + pxoff];      \
  }
#define STAGE(kk)                                                        \
  {                                                                      \
    _Pragma("unroll") for (int i = 0; i < 4; ++i) {                      \
      const int c = (kk) * 32 + tg * 4 + i;                              \
      const float s = s1s[c], b = b1s[c];                                \
      bf16x4 bv;                                                         \
      bv[0] = (__bf16)fmaxf(fmaf(v[i][0], s, b), 0.f);                   \
      bv[1] = (__bf16)fmaxf(fmaf(v[i][1], s, b), 0.f);                   \
      bv[2] = (__bf16)fmaxf(fmaf(v[i][2], s, b), 0.f);                   \
      bv[3] = (__bf16)fmaxf(fmaf(v[i][3], s, b), 0.f);                   \
      *(bf16x4*)&tile[(size_t)(tg * 4 + i) * 132 + 4 * l31] = bv;        \
    }                                                                    \
  }

  LOADV(0);

  for (int k = 0; k < 16; ++k) {
    STAGE(k);
    if (k < 15) LOADV(k + 1);
    __syncthreads();
    // fragments (u16 reads, 4-way tolerable) + MFMA
    bf16x8 bf[2];
#pragma unroll
    for (int g = 0; g < 2; ++g) {
      const int pl = wv * 32 + g * 16 + l15;
      bf16x8 tmp;
#pragma unroll
      for (int j = 0; j < 8; ++j)
        tmp[j] = __builtin_bit_cast(__bf16, tile[(kb * 8 + j) * 132 + pl]);
      bf[g] = tmp;
    }
#pragma unroll
    for (int m = 0; m < 8; ++m) {
      bf16x8 af = *(const bf16x8*)(w1b + (size_t)(m * 16 + l15) * 512 + k * 32 + kb * 8);
#pragma unroll
      for (int g = 0; g < 2; ++g)
        acc[m][g] = __builtin_amdgcn_mfma_f32_16x16x32_bf16(af, bf[g], acc[m][g], 0, 0, 0);
    }
    __syncthreads();
  }
#undef LOADV
#undef STAGE

  // epilogue: h2[n][p][oc] = relu(acc + bias2)  (plain stores -> cache for conv2)
#pragma unroll
  for (int m = 0; m < 8; ++m) {
    const int ocb = m * 16 + kb * 4;
    float bz0 = bias2[ocb + 0], bz1 = bias2[ocb + 1];
    float bz2 = bias2[ocb + 2], bz3 = bias2[ocb + 3];
#pragma unroll
    for (int g = 0; g < 2; ++g) {
      const int p = slab * 128 + wv * 32 + g * 16 + l15;
      bf16x4 hv;
      hv[0] = (__bf16)fmaxf(acc[m][g][0] + bz0, 0.f);
      hv[1] = (__bf16)fmaxf(acc[m][g][1] + bz1, 0.f);
      hv[2] = (__bf16)fmaxf(acc[m][g][2] + bz2, 0.f);
      hv[3] = (__bf16)fmaxf(acc[m][g][3] + bz3, 0.f);
      *(bf16x4*)(h2 + ((size_t)n * 1024 + p) * 128 + ocb) = hv;
    }
  }
}

// ---- kernel 3: 3x3 conv (pad 1) h2 -> out[:, 512:544] ----
// 1024 blocks (128 n x 8 slabs), 4 waves, wave = 32 oc x 32 px.
__global__ void __launch_bounds__(256) conv2_kernel(
    const unsigned short* __restrict__ h2, const unsigned short* __restrict__ w2b,
    float* __restrict__ out) {
  const int t = threadIdx.x;
  const int lane = t & 63;
  const int wv = t >> 6;
  const int n = blockIdx.x >> 3;
  const int pbase = (blockIdx.x & 7) * 128 + wv * 32;
  const int l15 = lane & 15;
  const int kb = lane >> 4;

  f32x4 acc[2][2];
#pragma unroll
  for (int m = 0; m < 2; ++m)
#pragma unroll
    for (int g = 0; g < 2; ++g) acc[m][g] = (f32x4){0.f, 0.f, 0.f, 0.f};

  const unsigned short* __restrict__ h2n = h2 + (size_t)n * 1024 * 128;

#pragma unroll
  for (int tap = 0; tap < 9; ++tap) {
    const int dy = tap / 3 - 1;
    const int dx = tap % 3 - 1;
#pragma unroll
    for (int c0 = 0; c0 < 128; c0 += 32) {
      const int cb = c0 + kb * 8;
      bf16x8 af[2];
#pragma unroll
      for (int m = 0; m < 2; ++m)
        af[m] = *(const bf16x8*)(w2b + (size_t)(m * 16 + l15) * 1152 + tap * 128 + cb);
#pragma unroll
      for (int g = 0; g < 2; ++g) {
        const int p = pbase + g * 16 + l15;
        const int y = (p >> 5) & 31;
        const int xx = p & 31;
        const int y2 = y + dy;
        const int x2 = xx + dx;
        bf16x8 bv = __builtin_bit_cast(bf16x8, (ushort8){0, 0, 0, 0, 0, 0, 0, 0});
        if (y2 >= 0 && y2 < 32 && x2 >= 0 && x2 < 32)
          bv = *(const bf16x8*)(h2n + ((size_t)(y2 * 32 + x2)) * 128 + cb);
#pragma unroll
        for (int m = 0; m < 2; ++m)
          acc[m][g] = __builtin_amdgcn_mfma_f32_16x16x32_bf16(af[m], bv, acc[m][g], 0, 0, 0);
      }
    }
  }

#pragma unroll
  for (int m = 0; m < 2; ++m) {
    const int oc = m * 16 + kb * 4;
#pragma unroll
    for (int g = 0; g < 2; ++g) {
      const int p = pbase + g * 16 + l15;
#pragma unroll
      for (int r = 0; r < 4; ++r)
        __builtin_nontemporal_store(
            acc[m][g][r], &out[((size_t)n * 544 + 512 + oc + r) * 1024 + p]);
    }
  }
}

extern "C" void kernel_launch(void* const* d_in, const int* in_sizes, int n_in,
                              void* d_out, int out_size, void* d_ws, size_t ws_size,
                              hipStream_t stream) {
  const float* x = (const float*)d_in[0];
  const float* gamma1 = (const float*)d_in[1];
  const float* beta1 = (const float*)d_in[2];
  const float* w1 = (const float*)d_in[3];
  const float* gamma2 = (const float*)d_in[4];
  const float* beta2 = (const float*)d_in[5];
  const float* mean2 = (const float*)d_in[6];
  const float* var2 = (const float*)d_in[7];
  const float* w2 = (const float*)d_in[8];
  float* out = (float*)d_out;

  char* ws = (char*)d_ws;
  unsigned short* h2 = (unsigned short*)ws;
  unsigned short* w1b = (unsigned short*)(ws + 33554432);
  unsigned short* w2b = (unsigned short*)(ws + 33685504);
  float* bias2 = (float*)(ws + 33759232);
  float* psum = (float*)(ws + 33763840);
  float* psq = (float*)(ws + 33780224);

  k1_kernel<<<4497, 256, 0, stream>>>(x, out, psum, psq,
                                      w1, gamma2, beta2, mean2, var2, w2,
                                      w1b, w2b, bias2);
  conv1_kernel<<<1024, 256, 0, stream>>>(x, w1b, psum, psq, gamma1, beta1,
                                         bias2, h2);
  conv2_kernel<<<1024, 256, 0, stream>>>(h2, w2b, out);
}

// Round 13
// 218.332 us; speedup vs baseline: 1.4000x; 1.0809x over previous
//
#include <hip/hip_runtime.h>

#define EPS 1e-5f

typedef __bf16 bf16x8 __attribute__((ext_vector_type(8)));
typedef __bf16 bf16x4 __attribute__((ext_vector_type(4)));
typedef unsigned short ushort8 __attribute__((ext_vector_type(8)));
typedef float f32x4 __attribute__((ext_vector_type(4)));

static __device__ __forceinline__ unsigned short f2bf(float f) {
  unsigned int u = __float_as_uint(f);
  u += 0x7fffu + ((u >> 16) & 1u);
  return (unsigned short)(u >> 16);
}

// ---------------- ws layout (bytes) ----------------
// h2   (bf16, NHWC [128][1024][128])             : 0 .. 33554432
// w1b  (bf16, [128 oc][512 c], bn2-scale folded) : 33554432 .. +131072
// w2b  (bf16, [32 oc][9 tap][128 c])             : 33685504 .. +73728
// bias2(f32 [128])                               : 33759232 .. +512
// s1   (f32 [512])                               : 33759744 .. +2048
// b1   (f32 [512])                               : 33761792 .. +2048
// psum (f32 [512][8])                            : 33763840 .. +16384
// psq  (f32 [512][8])                            : 33780224 .. +16384

// ---- kernel 1: bn1 partial stats + concat-copy of x (+ weight prep blocks) ----
// blocks 0..4095: (nq,c), nq-major so n=112..127 x-lines are freshest in L3.
// x loads PLAIN (allocate L3 for conv1 reuse); out stores nontemporal.
__global__ void __launch_bounds__(256) k1_kernel(
    const float* __restrict__ x, float* __restrict__ out,
    float* __restrict__ psum, float* __restrict__ psq,
    const float* __restrict__ w1, const float* __restrict__ gamma2,
    const float* __restrict__ beta2, const float* __restrict__ mean2,
    const float* __restrict__ var2, const float* __restrict__ w2,
    unsigned short* __restrict__ w1b, unsigned short* __restrict__ w2b,
    float* __restrict__ bias2) {
  const int t = threadIdx.x;
  if (blockIdx.x >= 4096) {
    int idx = (blockIdx.x - 4096) * 256 + t;
    if (idx < 128 * 512) {
      int oc = idx >> 9;
      float s2 = gamma2[oc] * rsqrtf(var2[oc] + EPS);
      w1b[idx] = f2bf(w1[idx] * s2);
    } else if (idx < 128 * 512 + 32 * 1152) {
      int i2 = idx - 128 * 512;
      int oc = i2 / 1152;
      int rem = i2 - oc * 1152;
      int tap = rem >> 7;
      int c = rem & 127;
      w2b[i2] = f2bf(w2[(oc * 128 + c) * 9 + tap]);
    } else if (idx < 128 * 512 + 32 * 1152 + 128) {
      int oc = idx - (128 * 512 + 32 * 1152);
      float s2 = gamma2[oc] * rsqrtf(var2[oc] + EPS);
      bias2[oc] = beta2[oc] - mean2[oc] * s2;
    }
    return;
  }
  const int c = blockIdx.x & 511;
  const int nq = blockIdx.x >> 9;
  float sum = 0.f, sq = 0.f;
  const f32x4* __restrict__ x4 = (const f32x4*)x;
  f32x4* out4 = (f32x4*)out;
#pragma unroll 8
  for (int i = 0; i < 16; ++i) {
    const int n = nq * 16 + i;
    f32x4 v = x4[(((size_t)n * 512 + c) << 8) + t];
    __builtin_nontemporal_store(v, &out4[(((size_t)n * 544 + c) << 8) + t]);
    sum += v[0] + v[1] + v[2] + v[3];
    sq += v[0] * v[0] + v[1] * v[1] + v[2] * v[2] + v[3] * v[3];
  }
  __shared__ float ls[2][4];
  for (int off = 32; off > 0; off >>= 1) {
    sum += __shfl_down(sum, off);
    sq += __shfl_down(sq, off);
  }
  const int w = t >> 6;
  if ((t & 63) == 0) { ls[0][w] = sum; ls[1][w] = sq; }
  __syncthreads();
  if (t == 0) {
    psum[c * 8 + nq] = ls[0][0] + ls[0][1] + ls[0][2] + ls[0][3];
    psq[c * 8 + nq] = ls[1][0] + ls[1][1] + ls[1][2] + ls[1][3];
  }
}

// ---- kernel 1b: finalize bn1 scale/shift (deterministic) ----
__global__ void reduce_kernel(const float* __restrict__ psum,
                              const float* __restrict__ psq,
                              const float* __restrict__ g1,
                              const float* __restrict__ be1,
                              float* __restrict__ s1, float* __restrict__ b1) {
  int c = blockIdx.x * 256 + threadIdx.x;
  if (c < 512) {
    float S = 0.f, Q = 0.f;
#pragma unroll
    for (int q = 0; q < 8; ++q) { S += psum[c * 8 + q]; Q += psq[c * 8 + q]; }
    float mean = S * (1.0f / 131072.0f);
    float var = Q * (1.0f / 131072.0f) - mean * mean;
    float s = g1[c] * rsqrtf(var + EPS);
    s1[c] = s;
    b1[c] = be1[c] - mean * s;
  }
}

// ---- kernel 2: bn1+relu -> 1x1 conv -> bn2+relu -> h2 (bf16 NHWC), direct from x ----
// EXACT R7 kernel (verified 199 us total). 512 blocks (128 n x 4 quarters),
// 4 waves; wave stages 8 ch x 256 px coalesced; LDS tile [32 ch][260 px].
__global__ void __launch_bounds__(256, 2) conv1_kernel(
    const float* __restrict__ x, const unsigned short* __restrict__ w1b,
    const float* __restrict__ s1, const float* __restrict__ b1,
    const float* __restrict__ bias2, unsigned short* __restrict__ h2) {
  const int t = threadIdx.x;
  __shared__ float s1s[512], b1s[512];
  __shared__ __align__(16) unsigned short tile[32 * 260];
  for (int cc = t; cc < 512; cc += 256) {
    s1s[cc] = s1[cc];
    b1s[cc] = b1[cc];
  }
  __syncthreads();

  const int lane = t & 63;
  const int wv = t >> 6;
  const int n = 127 - (blockIdx.x >> 2);
  const int q = blockIdx.x & 3;
  const int l15 = lane & 15;
  const int kb = lane >> 4;

  f32x4 acc[8][4];
#pragma unroll
  for (int m = 0; m < 8; ++m)
#pragma unroll
    for (int g = 0; g < 4; ++g) acc[m][g] = (f32x4){0.f, 0.f, 0.f, 0.f};

  // quarter base: x[n][.][q*256 ..]; f32x4 index = ch*256 + lane
  const f32x4* __restrict__ xq = (const f32x4*)(x + (size_t)n * 524288 + q * 256);

  f32x4 v[8];
#pragma unroll
  for (int i = 0; i < 8; ++i)
    v[i] = xq[(size_t)(wv * 8 + i) * 256 + lane];

  for (int k = 0; k < 16; ++k) {
    const int c0 = k * 32;
    // stage current K-slice (bn1+relu+cvt), prefetch next
#pragma unroll
    for (int i = 0; i < 8; ++i) {
      const int c = c0 + wv * 8 + i;
      const float s = s1s[c], b = b1s[c];
      bf16x4 bv;
      bv[0] = (__bf16)fmaxf(fmaf(v[i][0], s, b), 0.f);
      bv[1] = (__bf16)fmaxf(fmaf(v[i][1], s, b), 0.f);
      bv[2] = (__bf16)fmaxf(fmaf(v[i][2], s, b), 0.f);
      bv[3] = (__bf16)fmaxf(fmaf(v[i][3], s, b), 0.f);
      *(bf16x4*)&tile[(size_t)(wv * 8 + i) * 260 + 4 * lane] = bv;
    }
    if (k < 15) {
#pragma unroll
      for (int i = 0; i < 8; ++i)
        v[i] = xq[(size_t)(c0 + 32 + wv * 8 + i) * 256 + lane];
    }
    __syncthreads();
    // fragments (u16 reads, ~4-way) + MFMA
    bf16x8 bf[4];
#pragma unroll
    for (int g = 0; g < 4; ++g) {
      const int pl = wv * 64 + g * 16 + l15;
      bf16x8 tmp;
#pragma unroll
      for (int j = 0; j < 8; ++j)
        tmp[j] = __builtin_bit_cast(__bf16, tile[(kb * 8 + j) * 260 + pl]);
      bf[g] = tmp;
    }
#pragma unroll
    for (int m = 0; m < 8; ++m) {
      bf16x8 af = *(const bf16x8*)(w1b + (size_t)(m * 16 + l15) * 512 + c0 + kb * 8);
#pragma unroll
      for (int g = 0; g < 4; ++g)
        acc[m][g] = __builtin_amdgcn_mfma_f32_16x16x32_bf16(af, bf[g], acc[m][g], 0, 0, 0);
    }
    __syncthreads();
  }

  // epilogue: h2[n][p][oc] = relu(acc + bias2)  (plain stores -> cache for conv2)
#pragma unroll
  for (int m = 0; m < 8; ++m) {
    const int ocb = m * 16 + kb * 4;
    float bz0 = bias2[ocb + 0], bz1 = bias2[ocb + 1];
    float bz2 = bias2[ocb + 2], bz3 = bias2[ocb + 3];
#pragma unroll
    for (int g = 0; g < 4; ++g) {
      const int p = q * 256 + wv * 64 + g * 16 + l15;
      bf16x4 hv;
      hv[0] = (__bf16)fmaxf(acc[m][g][0] + bz0, 0.f);
      hv[1] = (__bf16)fmaxf(acc[m][g][1] + bz1, 0.f);
      hv[2] = (__bf16)fmaxf(acc[m][g][2] + bz2, 0.f);
      hv[3] = (__bf16)fmaxf(acc[m][g][3] + bz3, 0.f);
      *(bf16x4*)(h2 + ((size_t)n * 1024 + p) * 128 + ocb) = hv;
    }
  }
}

// ---- kernel 3: 3x3 conv (pad 1) h2 -> out[:, 512:544] ----
// 1024 blocks (128 n x 8 slabs), 4 waves, wave = 32 oc x 32 px (verified
// passing in R8/R10/R11). 4 blocks/CU for L2-latency hiding.
__global__ void __launch_bounds__(256) conv2_kernel(
    const unsigned short* __restrict__ h2, const unsigned short* __restrict__ w2b,
    float* __restrict__ out) {
  const int t = threadIdx.x;
  const int lane = t & 63;
  const int wv = t >> 6;
  const int n = blockIdx.x >> 3;
  const int pbase = (blockIdx.x & 7) * 128 + wv * 32;
  const int l15 = lane & 15;
  const int kb = lane >> 4;

  f32x4 acc[2][2];
#pragma unroll
  for (int m = 0; m < 2; ++m)
#pragma unroll
    for (int g = 0; g < 2; ++g) acc[m][g] = (f32x4){0.f, 0.f, 0.f, 0.f};

  const unsigned short* __restrict__ h2n = h2 + (size_t)n * 1024 * 128;

#pragma unroll
  for (int tap = 0; tap < 9; ++tap) {
    const int dy = tap / 3 - 1;
    const int dx = tap % 3 - 1;
#pragma unroll
    for (int c0 = 0; c0 < 128; c0 += 32) {
      const int cb = c0 + kb * 8;
      bf16x8 af[2];
#pragma unroll
      for (int m = 0; m < 2; ++m)
        af[m] = *(const bf16x8*)(w2b + (size_t)(m * 16 + l15) * 1152 + tap * 128 + cb);
#pragma unroll
      for (int g = 0; g < 2; ++g) {
        const int p = pbase + g * 16 + l15;
        const int y = (p >> 5) & 31;
        const int xx = p & 31;
        const int y2 = y + dy;
        const int x2 = xx + dx;
        bf16x8 bv = __builtin_bit_cast(bf16x8, (ushort8){0, 0, 0, 0, 0, 0, 0, 0});
        if (y2 >= 0 && y2 < 32 && x2 >= 0 && x2 < 32)
          bv = *(const bf16x8*)(h2n + ((size_t)(y2 * 32 + x2)) * 128 + cb);
#pragma unroll
        for (int m = 0; m < 2; ++m)
          acc[m][g] = __builtin_amdgcn_mfma_f32_16x16x32_bf16(af[m], bv, acc[m][g], 0, 0, 0);
      }
    }
  }

#pragma unroll
  for (int m = 0; m < 2; ++m) {
    const int oc = m * 16 + kb * 4;
#pragma unroll
    for (int g = 0; g < 2; ++g) {
      const int p = pbase + g * 16 + l15;
#pragma unroll
      for (int r = 0; r < 4; ++r)
        __builtin_nontemporal_store(
            acc[m][g][r], &out[((size_t)n * 544 + 512 + oc + r) * 1024 + p]);
    }
  }
}

extern "C" void kernel_launch(void* const* d_in, const int* in_sizes, int n_in,
                              void* d_out, int out_size, void* d_ws, size_t ws_size,
                              hipStream_t stream) {
  const float* x = (const float*)d_in[0];
  const float* gamma1 = (const float*)d_in[1];
  const float* beta1 = (const float*)d_in[2];
  const float* w1 = (const float*)d_in[3];
  const float* gamma2 = (const float*)d_in[4];
  const float* beta2 = (const float*)d_in[5];
  const float* mean2 = (const float*)d_in[6];
  const float* var2 = (const float*)d_in[7];
  const float* w2 = (const float*)d_in[8];
  float* out = (float*)d_out;

  char* ws = (char*)d_ws;
  unsigned short* h2 = (unsigned short*)ws;
  unsigned short* w1b = (unsigned short*)(ws + 33554432);
  unsigned short* w2b = (unsigned short*)(ws + 33685504);
  float* bias2 = (float*)(ws + 33759232);
  float* s1 = (float*)(ws + 33759744);
  float* b1 = (float*)(ws + 33761792);
  float* psum = (float*)(ws + 33763840);
  float* psq = (float*)(ws + 33780224);

  k1_kernel<<<4497, 256, 0, stream>>>(x, out, psum, psq,
                                      w1, gamma2, beta2, mean2, var2, w2,
                                      w1b, w2b, bias2);
  reduce_kernel<<<2, 256, 0, stream>>>(psum, psq, gamma1, beta1, s1, b1);
  conv1_kernel<<<512, 256, 0, stream>>>(x, w1b, s1, b1, bias2, h2);
  conv2_kernel<<<1024, 256, 0, stream>>>(h2, w2b, out);
}